// Round 5
// baseline (315.577 us; speedup 1.0000x reference)
//
#include <hip/hip_runtime.h>
#include <hip/hip_bf16.h>

typedef __hip_bfloat16 bf16;
typedef __attribute__((ext_vector_type(8))) short bf16x8;
typedef __attribute__((ext_vector_type(4))) float f32x4;

#define NNODE 512
#define NEDGE 16384
#define INLEN 17929
#define K1    1056   // 32 (u·S) + 512 (dist) + 512 (markov)

// ---- workspace layout (offsets in floats) ----
#define WS_EA      0         // 16384
#define WS_CSRC    16384     // 16384 (int)
#define WS_CEA     32768     // 16384
#define WS_DEG     49152     // 512 (int)
#define WS_STARTS  49664     // 512 (int)
#define WS_LATTR   50176     // 512
#define WS_MM      50688     // 2 (mn,mx)
#define WS_MMP     50690     // 128 (64 min partials, 64 max)
#define WS_STOPV   50818     // 512
#define WS_AE      51330     // 16 (AE1[8], AE2[8])
#define WS_PS      51346     // 4096 (16x256: j<8 src-proj, j>=8 dst-proj)
#define WS_H       55552     // 512*256
#define WS_X1      186624    // 512*256
#define WS_X2      317696    // 512*256
#define WS_ASRC    448768    // 512*8
#define WS_ADST    452864    // 512*8
#define WS_UV      456960    // 512*64 (u|v)
#define WS_K       489728    // 512
// bf16 buffers: element counts halved to FLOAT units correctly this time.
// 512*1056 bf16 = 540672 elems = 270336 floats; 512*512 bf16 = 131072 floats.
#define WS_APACK   490240    // bf16 512*1056 -> 270336 floats
#define WS_BPACK   760576    // bf16 512*1056 -> 270336 floats
#define WS_OUT1    1030912   // bf16 512*512  -> 131072 floats
#define WS_WC2B    1161984   // bf16 512*512  -> 131072 floats
#define WS_WESF    1293056   // 64*256 f32 = 16384
// end = 1309440 floats ≈ 5.2 MB

// ============ K1: fused prep ================================================
// b<512: layer-1 h + logits | b==512: stopv | b 513-514: packwes
// b 515-578: minmax partials | b 579-642: ea gather
__global__ __launch_bounds__(256)
void k_prep(const float* __restrict__ demand, const float* __restrict__ W1,
            const float* __restrict__ att_s, const float* __restrict__ att_d,
            const int* __restrict__ stops, const float* __restrict__ Wes,
            const float* __restrict__ dist, const float* __restrict__ markov,
            const int* __restrict__ eidx, float* ws){
  int b = blockIdx.x, tid = threadIdx.x;
  if (b < 512){
    int hd = tid>>5, c = tid&31;
    float hv = demand[b] * W1[tid];
    ws[WS_H + b*256 + tid] = hv;
    float ps = hv * att_s[tid];
    float pd = hv * att_d[tid];
    for (int off=16; off; off>>=1){ ps += __shfl_down(ps,off,32); pd += __shfl_down(pd,off,32); }
    if (c==0){ ws[WS_ASRC + b*8+hd]=ps; ws[WS_ADST + b*8+hd]=pd; }
  } else if (b == 512){
    ws[WS_STOPV+tid] = 0.f; ws[WS_STOPV+256+tid] = 0.f;
    __syncthreads();
    ws[WS_STOPV + stops[tid]] = 1.0f;
  } else if (b < 515){
    for (int idx = (b-513)*8192 + tid; idx < (b-512)*8192; idx += 256){
      int k = idx>>8, c = idx&255;
      ws[WS_WESF+idx] = (k<32) ? Wes[k*512+c] : Wes[(k-32)*512+256+c];
    }
  } else if (b < 579){
    __shared__ float smn[256], smx[256];
    int p = b-515;
    float mn = 3.4e38f, mx = -3.4e38f;
    for (int k=0;k<16;k++){
      float v = dist[p*4096 + k*256 + tid];
      mn = fminf(mn,v); mx = fmaxf(mx,v);
    }
    smn[tid]=mn; smx[tid]=mx; __syncthreads();
    for (int off=128; off; off>>=1){
      if (tid<off){ smn[tid]=fminf(smn[tid],smn[tid+off]); smx[tid]=fmaxf(smx[tid],smx[tid+off]); }
      __syncthreads();
    }
    if (tid==0){ ws[WS_MMP+p]=smn[0]; ws[WS_MMP+64+p]=smx[0]; }
  } else {
    int e = (b-579)*256 + tid;
    int r = eidx[e], c = eidx[NEDGE+e];
    ws[WS_EA+e] = markov[r*NNODE + c];
  }
}

// ============ K2: single-block graph build + small precomputes ==============
__global__ __launch_bounds__(512)
void k_graph(const int* __restrict__ eidx,
             const float* __restrict__ g1We, const float* __restrict__ g1ae,
             const float* __restrict__ g2We, const float* __restrict__ g2ae,
             const float* __restrict__ g2W,  const float* __restrict__ g2as,
             const float* __restrict__ g2ad, float* ws){
  __shared__ int   degS[512];
  __shared__ float lsumS[512];
  __shared__ int   curS[512];
  __shared__ int   sc[512];
  __shared__ int   startS[512];
  __shared__ float rmn[64], rmx[64];
  int t = threadIdx.x;
  // minmax final reduce
  if (t < 64){ rmn[t] = ws[WS_MMP+t]; rmx[t] = ws[WS_MMP+64+t]; }
  __syncthreads();
  if (t < 32){ rmn[t]=fminf(rmn[t],rmn[t+32]); rmx[t]=fmaxf(rmx[t],rmx[t+32]); }
  __syncthreads();
  if (t == 0){
    float mn=rmn[0], mx=rmx[0];
    for (int i=1;i<32;i++){ mn=fminf(mn,rmn[i]); mx=fmaxf(mx,rmx[i]); }
    ws[WS_MM]=mn; ws[WS_MM+1]=mx;
  }
  // AE dots (8 per layer)
  if (t < 8){
    float s=0.f; for (int c=0;c<32;c++) s += g1We[t*32+c]*g1ae[t*32+c];
    ws[WS_AE+t]=s;
  } else if (t < 16){
    int h=t-8; float s=0.f; for (int c=0;c<32;c++) s += g2We[h*32+c]*g2ae[h*32+c];
    ws[WS_AE+8+h]=s;
  }
  // PS/PD: 16x256, each thread 8 outputs x 32 MAC
  for (int oo=0; oo<8; oo++){
    int o = t*8+oo; int j = o>>8, n = o&255;
    const float* att = (j<8) ? g2as : g2ad;
    int h = j&7;
    float s=0.f;
    for (int c=0;c<32;c++) s += att[h*32+c] * g2W[(h*32+c)*256+n];
    ws[WS_PS+o]=s;
  }
  // graph: degree + lsum
  degS[t]=0; lsumS[t]=0.f; curS[t]=0;
  __syncthreads();
  for (int e=t; e<NEDGE; e+=512){
    int c = eidx[NEDGE+e];
    atomicAdd(&degS[c],1);
    atomicAdd(&lsumS[c], ws[WS_EA+e]);
  }
  __syncthreads();
  int d = degS[t];
  sc[t]=d; __syncthreads();
  for (int off=1; off<512; off<<=1){
    int v = (t>=off) ? sc[t-off] : 0; __syncthreads();
    sc[t]+=v; __syncthreads();
  }
  startS[t]=sc[t]-d;
  ((int*)(ws+WS_STARTS))[t]=startS[t];
  ((int*)(ws+WS_DEG))[t]=d;
  ws[WS_LATTR+t] = lsumS[t] / (float)(d>1 ? d : 1);
  __syncthreads();
  for (int e=t; e<NEDGE; e+=512){
    int c = eidx[NEDGE+e];
    int p = startS[c] + atomicAdd(&curS[c],1);
    ((int*)(ws+WS_CSRC))[p] = eidx[e];
    ws[WS_CEA+p] = ws[WS_EA+e];
  }
}

// ============ GAT online-softmax aggregate (+ optional UV epilogue) =========
template<bool DOUV>
__global__ __launch_bounds__(256)
void k_agg(const float* __restrict__ hbuf, const float* __restrict__ asrc,
           const float* __restrict__ adst, const int* __restrict__ csrc,
           const float* __restrict__ cea, const int* __restrict__ starts,
           const int* __restrict__ deg, const float* __restrict__ lattr,
           const float* __restrict__ AEp, const float* __restrict__ bvec,
           float* __restrict__ xout, const float* __restrict__ wesf,
           float* __restrict__ uv){
  int t = blockIdx.x, tid = threadIdx.x, hd = tid>>5;
  __shared__ float AE[8], m[8], den[8], alpha[8];
  __shared__ float L[32*8];
  __shared__ float xrow[256];
  if (tid < 8) AE[tid] = AEp[tid];
  __syncthreads();
  int d = deg[t], s0 = starts[t];
  if (tid < 8){
    float aself = asrc[t*8+tid] + adst[t*8+tid] + lattr[t]*AE[tid];
    aself = aself>=0.f ? aself : 0.2f*aself;
    m[tid] = aself; den[tid] = 1.0f;
  }
  __syncthreads();
  float acc = hbuf[t*256+tid];
  int el = tid>>3, h2 = tid&7;
  float adt2 = adst[t*8+h2], ae2 = AE[h2];
  for (int e0=0; e0<d; e0+=32){
    int ce = d-e0 < 32 ? d-e0 : 32;
    float lg = -3.4e38f;
    if (el < ce){
      int src = csrc[s0+e0+el];
      float a = asrc[src*8+h2] + adt2 + cea[s0+e0+el]*ae2;
      lg = a>=0.f ? a : 0.2f*a;
    }
    L[el*8+h2] = lg;
    __syncthreads();
    if (tid < 8){
      float mm = m[tid];
      for (int e=0;e<ce;e++) mm = fmaxf(mm, L[e*8+tid]);
      float al = __expf(m[tid]-mm);
      float dd = den[tid]*al;
      for (int e=0;e<ce;e++) dd += __expf(L[e*8+tid]-mm);
      m[tid]=mm; den[tid]=dd; alpha[tid]=al;
    }
    __syncthreads();
    if (el < ce) L[el*8+h2] = __expf(lg - m[h2]);
    __syncthreads();
    acc *= alpha[hd];
    for (int e=0;e<ce;e++){
      int sre = csrc[s0+e0+e];
      acc += L[e*8+hd] * hbuf[sre*256+tid];
    }
    __syncthreads();
  }
  float v = fmaxf(acc/den[hd] + bvec[tid], 0.f);
  xout[t*256+tid] = v;
  if (DOUV){
    xrow[tid] = v;
    __syncthreads();
    int k = tid>>2, q = tid&3;
    float p = 0.f;
    const float* wr = wesf + k*256 + q*64;
    const float* xr = xrow + q*64;
    for (int c=0;c<64;c++) p += xr[c]*wr[c];
    p += __shfl_down(p,2,4);
    p += __shfl_down(p,1,4);
    if (q==0) uv[t*64+k] = p;
  }
}

// ============ K4: gemm h2 = x1 @ g2W^T  +  logits GEMV ======================
__global__ __launch_bounds__(256)
void k_h2(const float* __restrict__ X1, const float* __restrict__ W2, float* ws){
  int b = blockIdx.x, tid = threadIdx.x;
  if (b < 128){
    __shared__ float As[32][34];
    __shared__ float Bs[32][34];
    const int bm = (b>>3)*32, bn = (b&7)*32;
    const int lr = tid>>3, lq = tid&7;
    const int tx = tid&15, ty = tid>>4;
    float a00=0.f, a01=0.f, a10=0.f, a11=0.f;
    const float* Ab = X1 + (size_t)(bm+lr)*256 + 4*lq;
    const float* Bb = W2 + (size_t)(bn+lr)*256 + 4*lq;
    for (int k0=0; k0<256; k0+=32){
      float4 av = *(const float4*)(Ab + k0);
      float4 bv = *(const float4*)(Bb + k0);
      As[4*lq+0][lr]=av.x; As[4*lq+1][lr]=av.y; As[4*lq+2][lr]=av.z; As[4*lq+3][lr]=av.w;
      Bs[4*lq+0][lr]=bv.x; Bs[4*lq+1][lr]=bv.y; Bs[4*lq+2][lr]=bv.z; Bs[4*lq+3][lr]=bv.w;
      __syncthreads();
      #pragma unroll
      for (int kk=0; kk<32; kk++){
        float2 a2 = *(const float2*)&As[kk][2*ty];
        float2 b2 = *(const float2*)&Bs[kk][2*tx];
        a00 += a2.x*b2.x; a01 += a2.x*b2.y; a10 += a2.y*b2.x; a11 += a2.y*b2.y;
      }
      __syncthreads();
    }
    int m0 = bm+2*ty, n0 = bn+2*tx;
    float* H = ws + WS_H;
    H[(size_t)m0*256+n0]     = a00; H[(size_t)m0*256+n0+1]     = a01;
    H[(size_t)(m0+1)*256+n0] = a10; H[(size_t)(m0+1)*256+n0+1] = a11;
  } else {
    int p0 = ((b-128)*256 + tid)*4;
    int n = p0>>4, j0 = p0&15;
    const float* xr = X1 + n*256;
    #pragma unroll
    for (int r=0;r<4;r++){
      int j = j0+r;
      const float* pr = ws + WS_PS + j*256;
      float s = 0.f;
      for (int c=0;c<256;c++) s += xr[c]*pr[c];
      if (j<8) ws[WS_ASRC + n*8+j] = s;
      else     ws[WS_ADST + n*8+(j-8)] = s;
    }
  }
}

// ============ K6: fused sk+packB (b<512) and packA (b>=512) =================
__global__ __launch_bounds__(256)
void k_skpack(const float* __restrict__ Wc1, const float* __restrict__ bc1,
              const float* __restrict__ bes, const float* __restrict__ Wweek,
              const float* __restrict__ Wcap, const float* __restrict__ Wveh,
              const int* __restrict__ wd, const int* __restrict__ vh,
              const int* __restrict__ cp, const float* __restrict__ Wc2,
              const float* __restrict__ dist, const float* __restrict__ markov,
              float* ws){
  int b = blockIdx.x, tid = threadIdx.x;
  if (b < 512){
    int o = b;
    __shared__ float besf[32];
    __shared__ float red[256];
    if (tid<32) besf[tid] = bes[tid];
    __syncthreads();
    const float* wr = Wc1 + (size_t)o*INLEN;
    const float* UV = ws + WS_UV;
    bf16* bp  = (bf16*)(ws+WS_BPACK);
    bf16* w2b = (bf16*)(ws+WS_WC2B);
    float sP = 0.f, tP = 0.f;
    for (int idx=tid; idx<16384; idx+=256){
      float wv = wr[idx];
      sP += wv;
      tP += wv * (UV[((idx>>5)<<6) + 32 + (idx&31)] + besf[idx&31]);
    }
    for (int j=tid; j<512; j+=256) tP += ws[WS_STOPV+j] * wr[17417+j];
    if (tid < 9){
      int g = tid/3, f = tid-g*3;
      float sv = (g==0) ? Wweek[wd[0]*3+f]
               : (g==1) ? Wcap[cp[0]*3+f]
                        : Wveh[vh[0]*3+f];
      tP += sv * wr[17408+tid];
    }
    red[tid] = sP; __syncthreads();
    if (tid<32){
      float s=0.f; for (int q=0;q<8;q++) s += red[tid+32*q];
      bp[(size_t)o*K1 + tid] = __float2bfloat16(s);
    }
    __syncthreads();
    red[tid] = tP; __syncthreads();
    for (int off=128; off; off>>=1){ if (tid<off) red[tid] += red[tid+off]; __syncthreads(); }
    if (tid==0) ws[WS_K+o] = red[0] + bc1[o];
    for (int j=tid; j<1024; j+=256)
      bp[(size_t)o*K1 + 32 + j] = __float2bfloat16(wr[16384+j]);
    for (int j=tid; j<512; j+=256)
      w2b[o*512+j] = __float2bfloat16(Wc2[o*512+j]);
  } else {
    int i = b-512;
    float mn = ws[WS_MM], mx = ws[WS_MM+1];
    float inv = 1.0f/(mx-mn);
    bf16* ap = (bf16*)(ws+WS_APACK);
    for (int j=tid; j<K1; j+=256){
      float v;
      if (j<32)       v = ws[WS_UV + i*64 + j];
      else if (j<544) v = (dist[i*512 + j-32] - mn) * inv;
      else            v = markov[i*512 + j-544];
      ap[(size_t)i*K1 + j] = __float2bfloat16(v);
    }
  }
}

// ============ bf16 MFMA GEMM: C = A(MxK)·B(NxK)^T, 64x64 tile ==============
template<bool RELU, bool BF16OUT>
__global__ __launch_bounds__(256)
void gemm_mfma(const bf16* __restrict__ A, const bf16* __restrict__ B,
               const float* __restrict__ bias, float* __restrict__ Cf,
               bf16* __restrict__ Cb, int M, int N, int K){
  __shared__ short Als[2048];
  __shared__ short Bls[2048];
  const int tid = threadIdx.x;
  const int bm = blockIdx.y*64, bn = blockIdx.x*64;
  const int wave = tid>>6, lane = tid&63;
  const int wm = wave>>1, wn = wave&1;
  const int r = lane&15, q = lane>>4;
  f32x4 acc[2][2] = {};
  const int lrow = tid>>2, lq = tid&3;
  const bf16* Ag = A + (size_t)(bm+lrow)*K + lq*8;
  const bf16* Bg = B + (size_t)(bn+lrow)*K + lq*8;
  const int sidx = (lq*64+lrow)*8;
  for (int k0=0; k0<K; k0+=32){
    float4 av = *(const float4*)(Ag + k0);
    float4 bv = *(const float4*)(Bg + k0);
    *(float4*)(&Als[sidx]) = av;
    *(float4*)(&Bls[sidx]) = bv;
    __syncthreads();
    #pragma unroll
    for (int i=0;i<2;i++){
      bf16x8 af = *(const bf16x8*)(&Als[(q*64 + wm*32 + i*16 + r)*8]);
      #pragma unroll
      for (int j=0;j<2;j++){
        bf16x8 bfr = *(const bf16x8*)(&Bls[(q*64 + wn*32 + j*16 + r)*8]);
        acc[i][j] = __builtin_amdgcn_mfma_f32_16x16x32_bf16(af, bfr, acc[i][j], 0,0,0);
      }
    }
    __syncthreads();
  }
  #pragma unroll
  for (int i=0;i<2;i++){
    int row = bm + wm*32 + i*16 + q*4;
    #pragma unroll
    for (int j=0;j<2;j++){
      int col = bn + wn*32 + j*16 + r;
      float bi = bias ? bias[col] : 0.f;
      #pragma unroll
      for (int g=0; g<4; g++){
        float v = acc[i][j][g] + bi;
        if (RELU) v = fmaxf(v, 0.f);
        if (BF16OUT) Cb[(size_t)(row+g)*N + col] = __float2bfloat16(v);
        else         Cf[(size_t)(row+g)*N + col] = v;
      }
    }
  }
}

extern "C" void kernel_launch(void* const* d_in, const int* in_sizes, int n_in,
                              void* d_out, int out_size, void* d_ws, size_t ws_size,
                              hipStream_t stream){
  const float* dist   = (const float*)d_in[0];
  const float* markov = (const float*)d_in[1];
  const float* demand = (const float*)d_in[2];
  const float* Wweek  = (const float*)d_in[3];
  const float* Wcap   = (const float*)d_in[4];
  const float* Wveh   = (const float*)d_in[5];
  const float* g1W    = (const float*)d_in[6];
  const float* g1as   = (const float*)d_in[7];
  const float* g1ad   = (const float*)d_in[8];
  const float* g1We   = (const float*)d_in[9];
  const float* g1ae   = (const float*)d_in[10];
  const float* g1b    = (const float*)d_in[11];
  const float* g2W    = (const float*)d_in[12];
  const float* g2as   = (const float*)d_in[13];
  const float* g2ad   = (const float*)d_in[14];
  const float* g2We   = (const float*)d_in[15];
  const float* g2ae   = (const float*)d_in[16];
  const float* g2b    = (const float*)d_in[17];
  const float* Wes    = (const float*)d_in[18];
  const float* bes    = (const float*)d_in[19];
  const float* Wc1    = (const float*)d_in[20];
  const float* bc1    = (const float*)d_in[21];
  const float* Wc2    = (const float*)d_in[22];
  const float* bc2    = (const float*)d_in[23];
  const int*   stops  = (const int*)d_in[24];
  const int*   eidx   = (const int*)d_in[25];
  const int*   wd     = (const int*)d_in[26];
  const int*   vh     = (const int*)d_in[27];
  const int*   cp     = (const int*)d_in[28];
  float* out = (float*)d_out;
  float* ws = (float*)d_ws;

  const int*   csrc   = (const int*)(ws+WS_CSRC);
  const float* cea    = ws+WS_CEA;
  const int*   starts = (const int*)(ws+WS_STARTS);
  const int*   deg    = (const int*)(ws+WS_DEG);
  const float* lattr  = ws+WS_LATTR;

  // K1: all input-only prep (h1+logits1, stopv, wes pack, minmax, ea gather)
  k_prep<<<643,256,0,stream>>>(demand, g1W, g1as, g1ad, stops, Wes, dist, markov, eidx, ws);
  // K2: single-block graph build + AE/PS precompute + minmax reduce
  k_graph<<<1,512,0,stream>>>(eidx, g1We, g1ae, g2We, g2ae, g2W, g2as, g2ad, ws);
  // K3: GAT layer-1 aggregate
  k_agg<false><<<512,256,0,stream>>>(ws+WS_H, ws+WS_ASRC, ws+WS_ADST, csrc, cea, starts, deg,
                                     lattr, ws+WS_AE, g1b, ws+WS_X1, nullptr, nullptr);
  // K4: h2 gemm + layer-2 logits GEMV
  k_h2<<<136,256,0,stream>>>(ws+WS_X1, g2W, ws);
  // K5: GAT layer-2 aggregate + UV epilogue
  k_agg<true><<<512,256,0,stream>>>(ws+WS_H, ws+WS_ASRC, ws+WS_ADST, csrc, cea, starts, deg,
                                    lattr, ws+WS_AE+8, g2b, ws+WS_X2, ws+WS_WESF, ws+WS_UV);
  // K6: sk + packB + Wc2->bf16 + packA
  k_skpack<<<1024,256,0,stream>>>(Wc1, bc1, bes, Wweek, Wcap, Wveh, wd, vh, cp, Wc2,
                                  dist, markov, ws);
  // K7/K8: decoder MFMA GEMMs
  gemm_mfma<true,true><<<dim3(8,8),256,0,stream>>>((const bf16*)(ws+WS_APACK), (const bf16*)(ws+WS_BPACK),
                                                   ws+WS_K, nullptr, (bf16*)(ws+WS_OUT1), 512, 512, K1);
  gemm_mfma<false,false><<<dim3(8,8),256,0,stream>>>((const bf16*)(ws+WS_OUT1), (const bf16*)(ws+WS_WC2B),
                                                     bc2, out, nullptr, 512, 512, 512);
}

// Round 6
// 269.590 us; speedup vs baseline: 1.1706x; 1.1706x over previous
//
#include <hip/hip_runtime.h>
#include <hip/hip_bf16.h>

typedef __hip_bfloat16 bf16;
typedef __attribute__((ext_vector_type(8))) short bf16x8;
typedef __attribute__((ext_vector_type(4))) float f32x4;

#define NNODE 512
#define NEDGE 16384
#define INLEN 17929
#define K1    1056   // 32 (u·S) + 512 (dist) + 512 (markov)

// ---- workspace layout (offsets in floats) ----
#define WS_EA      0         // 16384
#define WS_CSRC    16384     // 16384 (int)
#define WS_CEA     32768     // 16384
#define WS_DEG     49152     // 512 (int)
#define WS_STARTS  49664     // 512 (int)
#define WS_LATTR   50176     // 512
#define WS_MM      50688     // 2 (mn,mx)
#define WS_MMP     50690     // 128 (64 min partials, 64 max)
#define WS_STOPV   50818     // 512
#define WS_AE      51330     // 16 (AE1[8], AE2[8])
#define WS_PS      51346     // 4096 (16x256: j<8 src-proj, j>=8 dst-proj)
#define WS_H       55552     // 512*256 (layer-1 h)
#define WS_G2WT    186624    // 256*256 (g2W transposed)
#define WS_H2      317696    // 512*256 (layer-2 h)
#define WS_ASRC    448768    // 512*8 (layer-1)
#define WS_ADST    452864    // 512*8
#define WS_UV      456960    // 512*64 (u|v)
#define WS_K       489728    // 512
#define WS_APACK   490240    // bf16 512*1056 -> 270336 floats
#define WS_BPACK   760576    // bf16 512*1056 -> 270336 floats
#define WS_OUT1    1030912   // bf16 512*512  -> 131072 floats
#define WS_WC2B    1161984   // bf16 512*512  -> 131072 floats
#define WS_WESF    1293056   // 64*256 f32
#define WS_ASRC2   1309440   // 512*8 (layer-2)
#define WS_ADST2   1313536   // 512*8
// end = 1317632 floats ≈ 5.3 MB

// ============ K1: fused prep (all input-only, fully parallel) ===============
// b<512: layer-1 h + logits | b==512: stopv + AE dots | b 513-514: wes pack
// b 515-578: minmax partials | b 579-642: ea gather | b 643-658: PS/PD
// b 659-674: g2W transpose
__global__ __launch_bounds__(256)
void k_prep(const float* __restrict__ demand, const float* __restrict__ W1,
            const float* __restrict__ att_s, const float* __restrict__ att_d,
            const int* __restrict__ stops, const float* __restrict__ Wes,
            const float* __restrict__ dist, const float* __restrict__ markov,
            const int* __restrict__ eidx,
            const float* __restrict__ g1We, const float* __restrict__ g1ae,
            const float* __restrict__ g2We, const float* __restrict__ g2ae,
            const float* __restrict__ g2W,  const float* __restrict__ g2as,
            const float* __restrict__ g2ad, float* ws){
  int b = blockIdx.x, tid = threadIdx.x;
  if (b < 512){
    int hd = tid>>5, c = tid&31;
    float hv = demand[b] * W1[tid];
    ws[WS_H + b*256 + tid] = hv;
    float ps = hv * att_s[tid];
    float pd = hv * att_d[tid];
    for (int off=16; off; off>>=1){ ps += __shfl_down(ps,off,32); pd += __shfl_down(pd,off,32); }
    if (c==0){ ws[WS_ASRC + b*8+hd]=ps; ws[WS_ADST + b*8+hd]=pd; }
  } else if (b == 512){
    ws[WS_STOPV+tid] = 0.f; ws[WS_STOPV+256+tid] = 0.f;
    __syncthreads();
    ws[WS_STOPV + stops[tid]] = 1.0f;
    if (tid < 8){
      float s=0.f; for (int c=0;c<32;c++) s += g1We[tid*32+c]*g1ae[tid*32+c];
      ws[WS_AE+tid]=s;
    } else if (tid < 16){
      int h=tid-8; float s=0.f; for (int c=0;c<32;c++) s += g2We[h*32+c]*g2ae[h*32+c];
      ws[WS_AE+8+h]=s;
    }
  } else if (b < 515){
    for (int idx = (b-513)*8192 + tid; idx < (b-512)*8192; idx += 256){
      int k = idx>>8, c = idx&255;
      ws[WS_WESF+idx] = (k<32) ? Wes[k*512+c] : Wes[(k-32)*512+256+c];
    }
  } else if (b < 579){
    __shared__ float smn[256], smx[256];
    int p = b-515;
    float mn = 3.4e38f, mx = -3.4e38f;
    for (int k=0;k<16;k++){
      float v = dist[p*4096 + k*256 + tid];
      mn = fminf(mn,v); mx = fmaxf(mx,v);
    }
    smn[tid]=mn; smx[tid]=mx; __syncthreads();
    for (int off=128; off; off>>=1){
      if (tid<off){ smn[tid]=fminf(smn[tid],smn[tid+off]); smx[tid]=fmaxf(smx[tid],smx[tid+off]); }
      __syncthreads();
    }
    if (tid==0){ ws[WS_MMP+p]=smn[0]; ws[WS_MMP+64+p]=smx[0]; }
  } else if (b < 643){
    int e = (b-579)*256 + tid;
    int r = eidx[e], c = eidx[NEDGE+e];
    ws[WS_EA+e] = markov[r*NNODE + c];
  } else if (b < 659){
    // PS/PD: lane n coalesced over g2W columns
    int j = b-643;
    const float* att = (j<8) ? g2as : g2ad;
    int h = j&7;
    float s = 0.f;
    for (int c=0;c<32;c++) s += att[h*32+c] * g2W[(h*32+c)*256 + tid];
    ws[WS_PS + j*256 + tid] = s;
  } else {
    // g2W transpose, 64x64 LDS tiles (+1 pad)
    __shared__ float T[64][65];
    int tb = b-659, tr = tb>>2, tc = tb&3;
    int w = tid>>6, c = tid&63;
    for (int k=0;k<16;k++){
      int r = k*4 + w;
      T[r][c] = g2W[(tr*64+r)*256 + tc*64 + c];
    }
    __syncthreads();
    for (int k=0;k<16;k++){
      int r = k*4 + w;
      ws[WS_G2WT + (tc*64+r)*256 + tr*64 + c] = T[c][r];
    }
  }
}

// ============ K2: single-block graph build (histogram/scan/scatter only) ====
__global__ __launch_bounds__(512)
void k_graph(const int* __restrict__ eidx, float* ws){
  __shared__ int   degS[512];
  __shared__ float lsumS[512];
  __shared__ int   curS[512];
  __shared__ int   sc[512];
  __shared__ int   startS[512];
  __shared__ float rmn[64], rmx[64];
  int t = threadIdx.x;
  if (t < 64){ rmn[t] = ws[WS_MMP+t]; rmx[t] = ws[WS_MMP+64+t]; }
  __syncthreads();
  if (t < 32){ rmn[t]=fminf(rmn[t],rmn[t+32]); rmx[t]=fmaxf(rmx[t],rmx[t+32]); }
  __syncthreads();
  if (t == 0){
    float mn=rmn[0], mx=rmx[0];
    for (int i=1;i<32;i++){ mn=fminf(mn,rmn[i]); mx=fmaxf(mx,rmx[i]); }
    ws[WS_MM]=mn; ws[WS_MM+1]=mx;
  }
  degS[t]=0; lsumS[t]=0.f; curS[t]=0;
  __syncthreads();
  for (int e=t; e<NEDGE; e+=512){
    int c = eidx[NEDGE+e];
    atomicAdd(&degS[c],1);
    atomicAdd(&lsumS[c], ws[WS_EA+e]);
  }
  __syncthreads();
  int d = degS[t];
  sc[t]=d; __syncthreads();
  for (int off=1; off<512; off<<=1){
    int v = (t>=off) ? sc[t-off] : 0; __syncthreads();
    sc[t]+=v; __syncthreads();
  }
  startS[t]=sc[t]-d;
  ((int*)(ws+WS_STARTS))[t]=startS[t];
  ((int*)(ws+WS_DEG))[t]=d;
  ws[WS_LATTR+t] = lsumS[t] / (float)(d>1 ? d : 1);
  __syncthreads();
  for (int e=t; e<NEDGE; e+=512){
    int c = eidx[NEDGE+e];
    int p = startS[c] + atomicAdd(&curS[c],1);
    ((int*)(ws+WS_CSRC))[p] = eidx[e];
    ws[WS_CEA+p] = ws[WS_EA+e];
  }
}

// ============ GAT aggregate; MODE 1: +h2+logits2 epi, MODE 2: +uv+packA epi =
template<int MODE>
__global__ __launch_bounds__(256)
void k_agg(const float* __restrict__ hbuf, const float* __restrict__ asrc,
           const float* __restrict__ adst, const int* __restrict__ csrc,
           const float* __restrict__ cea, const int* __restrict__ starts,
           const int* __restrict__ deg, const float* __restrict__ lattr,
           const float* __restrict__ AEp, const float* __restrict__ bvec,
           const float* __restrict__ dist, const float* __restrict__ markov,
           float* ws){
  int t = blockIdx.x, tid = threadIdx.x, hd = tid>>5;
  __shared__ float AE[8], m[8], den[8], alpha[8];
  __shared__ float L[32*8];
  __shared__ float xrow[256];
  __shared__ float uvrow[64];
  if (tid < 8) AE[tid] = AEp[tid];
  __syncthreads();
  int d = deg[t], s0 = starts[t];
  if (tid < 8){
    float aself = asrc[t*8+tid] + adst[t*8+tid] + lattr[t]*AE[tid];
    aself = aself>=0.f ? aself : 0.2f*aself;
    m[tid] = aself; den[tid] = 1.0f;
  }
  __syncthreads();
  float acc = hbuf[t*256+tid];
  int el = tid>>3, h2i = tid&7;
  float adt2 = adst[t*8+h2i], ae2 = AE[h2i];
  for (int e0=0; e0<d; e0+=32){
    int ce = d-e0 < 32 ? d-e0 : 32;
    float lg = -3.4e38f;
    if (el < ce){
      int src = csrc[s0+e0+el];
      float a = asrc[src*8+h2i] + adt2 + cea[s0+e0+el]*ae2;
      lg = a>=0.f ? a : 0.2f*a;
    }
    L[el*8+h2i] = lg;
    __syncthreads();
    if (tid < 8){
      float mm = m[tid];
      for (int e=0;e<ce;e++) mm = fmaxf(mm, L[e*8+tid]);
      float al = __expf(m[tid]-mm);
      float dd = den[tid]*al;
      for (int e=0;e<ce;e++) dd += __expf(L[e*8+tid]-mm);
      m[tid]=mm; den[tid]=dd; alpha[tid]=al;
    }
    __syncthreads();
    if (el < ce) L[el*8+h2i] = __expf(lg - m[h2i]);
    __syncthreads();
    acc *= alpha[hd];
    for (int e=0;e<ce;e++){
      int sre = csrc[s0+e0+e];
      acc += L[e*8+hd] * hbuf[sre*256+tid];
    }
    __syncthreads();
  }
  float v = fmaxf(acc/den[hd] + bvec[tid], 0.f);
  xrow[tid] = v;
  __syncthreads();
  if (MODE == 1){
    // h2 row: xrow @ g2W^T via pre-transposed g2WT (coalesced over tid)
    const float* g2wt = ws + WS_G2WT;
    float hr = 0.f;
    for (int c=0;c<256;c++) hr += xrow[c] * g2wt[c*256 + tid];
    ws[WS_H2 + t*256 + tid] = hr;
    // layer-2 logits via PS: a2[t,j] = xrow · PS[j,:]
    if (tid < 64){
      int j = tid>>2, q = tid&3;
      const float* pr = ws + WS_PS + j*256 + q*64;
      const float* xr = xrow + q*64;
      float p = 0.f;
      for (int c=0;c<64;c++) p += xr[c]*pr[c];
      p += __shfl_down(p,2,4);
      p += __shfl_down(p,1,4);
      if (q==0){
        if (j<8) ws[WS_ASRC2 + t*8+j] = p;
        else     ws[WS_ADST2 + t*8+(j-8)] = p;
      }
    }
  } else {
    // uv row
    int k = tid>>2, q = tid&3;
    const float* wr = ws + WS_WESF + k*256 + q*64;
    const float* xr = xrow + q*64;
    float p = 0.f;
    for (int c=0;c<64;c++) p += xr[c]*wr[c];
    p += __shfl_down(p,2,4);
    p += __shfl_down(p,1,4);
    if (q==0){ ws[WS_UV + t*64+k] = p; uvrow[k] = p; }
    __syncthreads();
    // packA row (bf16)
    float mn = ws[WS_MM], mx = ws[WS_MM+1];
    float inv = 1.0f/(mx-mn);
    bf16* ap = (bf16*)(ws+WS_APACK);
    for (int j=tid; j<K1; j+=256){
      float v2;
      if (j<32)       v2 = uvrow[j];
      else if (j<544) v2 = (dist[t*512 + j-32] - mn) * inv;
      else            v2 = markov[t*512 + j-544];
      ap[(size_t)t*K1 + j] = __float2bfloat16(v2);
    }
  }
}

// ============ K5: fused sk+packB + Wc2->bf16 ================================
__global__ __launch_bounds__(256)
void k_skpack(const float* __restrict__ Wc1, const float* __restrict__ bc1,
              const float* __restrict__ bes, const float* __restrict__ Wweek,
              const float* __restrict__ Wcap, const float* __restrict__ Wveh,
              const int* __restrict__ wd, const int* __restrict__ vh,
              const int* __restrict__ cp, const float* __restrict__ Wc2,
              float* ws){
  int o = blockIdx.x, tid = threadIdx.x;
  __shared__ float besf[32];
  __shared__ float red[256];
  if (tid<32) besf[tid] = bes[tid];
  __syncthreads();
  const float* wr = Wc1 + (size_t)o*INLEN;
  const float* UV = ws + WS_UV;
  bf16* bp  = (bf16*)(ws+WS_BPACK);
  bf16* w2b = (bf16*)(ws+WS_WC2B);
  float sP = 0.f, tP = 0.f;
  for (int idx=tid; idx<16384; idx+=256){
    float wv = wr[idx];
    sP += wv;
    tP += wv * (UV[((idx>>5)<<6) + 32 + (idx&31)] + besf[idx&31]);
  }
  for (int j=tid; j<512; j+=256) tP += ws[WS_STOPV+j] * wr[17417+j];
  if (tid < 9){
    int g = tid/3, f = tid-g*3;
    float sv = (g==0) ? Wweek[wd[0]*3+f]
             : (g==1) ? Wcap[cp[0]*3+f]
                      : Wveh[vh[0]*3+f];
    tP += sv * wr[17408+tid];
  }
  red[tid] = sP; __syncthreads();
  if (tid<32){
    float s=0.f; for (int q=0;q<8;q++) s += red[tid+32*q];
    bp[(size_t)o*K1 + tid] = __float2bfloat16(s);
  }
  __syncthreads();
  red[tid] = tP; __syncthreads();
  for (int off=128; off; off>>=1){ if (tid<off) red[tid] += red[tid+off]; __syncthreads(); }
  if (tid==0) ws[WS_K+o] = red[0] + bc1[o];
  for (int j=tid; j<1024; j+=256)
    bp[(size_t)o*K1 + 32 + j] = __float2bfloat16(wr[16384+j]);
  for (int j=tid; j<512; j+=256)
    w2b[o*512+j] = __float2bfloat16(Wc2[o*512+j]);
}

// ============ bf16 MFMA GEMM: C = A(MxK)·B(NxK)^T, 64x64 tile ==============
template<bool RELU, bool BF16OUT>
__global__ __launch_bounds__(256)
void gemm_mfma(const bf16* __restrict__ A, const bf16* __restrict__ B,
               const float* __restrict__ bias, float* __restrict__ Cf,
               bf16* __restrict__ Cb, int M, int N, int K){
  __shared__ short Als[2048];
  __shared__ short Bls[2048];
  const int tid = threadIdx.x;
  const int bm = blockIdx.y*64, bn = blockIdx.x*64;
  const int wave = tid>>6, lane = tid&63;
  const int wm = wave>>1, wn = wave&1;
  const int r = lane&15, q = lane>>4;
  f32x4 acc[2][2] = {};
  const int lrow = tid>>2, lq = tid&3;
  const bf16* Ag = A + (size_t)(bm+lrow)*K + lq*8;
  const bf16* Bg = B + (size_t)(bn+lrow)*K + lq*8;
  const int sidx = (lq*64+lrow)*8;
  for (int k0=0; k0<K; k0+=32){
    float4 av = *(const float4*)(Ag + k0);
    float4 bv = *(const float4*)(Bg + k0);
    *(float4*)(&Als[sidx]) = av;
    *(float4*)(&Bls[sidx]) = bv;
    __syncthreads();
    #pragma unroll
    for (int i=0;i<2;i++){
      bf16x8 af = *(const bf16x8*)(&Als[(q*64 + wm*32 + i*16 + r)*8]);
      #pragma unroll
      for (int j=0;j<2;j++){
        bf16x8 bfr = *(const bf16x8*)(&Bls[(q*64 + wn*32 + j*16 + r)*8]);
        acc[i][j] = __builtin_amdgcn_mfma_f32_16x16x32_bf16(af, bfr, acc[i][j], 0,0,0);
      }
    }
    __syncthreads();
  }
  #pragma unroll
  for (int i=0;i<2;i++){
    int row = bm + wm*32 + i*16 + q*4;
    #pragma unroll
    for (int j=0;j<2;j++){
      int col = bn + wn*32 + j*16 + r;
      float bi = bias ? bias[col] : 0.f;
      #pragma unroll
      for (int g=0; g<4; g++){
        float v = acc[i][j][g] + bi;
        if (RELU) v = fmaxf(v, 0.f);
        if (BF16OUT) Cb[(size_t)(row+g)*N + col] = __float2bfloat16(v);
        else         Cf[(size_t)(row+g)*N + col] = v;
      }
    }
  }
}

extern "C" void kernel_launch(void* const* d_in, const int* in_sizes, int n_in,
                              void* d_out, int out_size, void* d_ws, size_t ws_size,
                              hipStream_t stream){
  const float* dist   = (const float*)d_in[0];
  const float* markov = (const float*)d_in[1];
  const float* demand = (const float*)d_in[2];
  const float* Wweek  = (const float*)d_in[3];
  const float* Wcap   = (const float*)d_in[4];
  const float* Wveh   = (const float*)d_in[5];
  const float* g1W    = (const float*)d_in[6];
  const float* g1as   = (const float*)d_in[7];
  const float* g1ad   = (const float*)d_in[8];
  const float* g1We   = (const float*)d_in[9];
  const float* g1ae   = (const float*)d_in[10];
  const float* g1b    = (const float*)d_in[11];
  const float* g2W    = (const float*)d_in[12];
  const float* g2as   = (const float*)d_in[13];
  const float* g2ad   = (const float*)d_in[14];
  const float* g2We   = (const float*)d_in[15];
  const float* g2ae   = (const float*)d_in[16];
  const float* g2b    = (const float*)d_in[17];
  const float* Wes    = (const float*)d_in[18];
  const float* bes    = (const float*)d_in[19];
  const float* Wc1    = (const float*)d_in[20];
  const float* bc1    = (const float*)d_in[21];
  const float* Wc2    = (const float*)d_in[22];
  const float* bc2    = (const float*)d_in[23];
  const int*   stops  = (const int*)d_in[24];
  const int*   eidx   = (const int*)d_in[25];
  const int*   wd     = (const int*)d_in[26];
  const int*   vh     = (const int*)d_in[27];
  const int*   cp     = (const int*)d_in[28];
  float* out = (float*)d_out;
  float* ws = (float*)d_ws;

  const int*   csrc   = (const int*)(ws+WS_CSRC);
  const float* cea    = ws+WS_CEA;
  const int*   starts = (const int*)(ws+WS_STARTS);
  const int*   deg    = (const int*)(ws+WS_DEG);
  const float* lattr  = ws+WS_LATTR;

  // K1: all input-only prep
  k_prep<<<675,256,0,stream>>>(demand, g1W, g1as, g1ad, stops, Wes, dist, markov, eidx,
                               g1We, g1ae, g2We, g2ae, g2W, g2as, g2ad, ws);
  // K2: single-block graph build only
  k_graph<<<1,512,0,stream>>>(eidx, ws);
  // K3: GAT layer-1 aggregate + h2 + logits-2 epilogue
  k_agg<1><<<512,256,0,stream>>>(ws+WS_H, ws+WS_ASRC, ws+WS_ADST, csrc, cea, starts, deg,
                                 lattr, ws+WS_AE, g1b, dist, markov, ws);
  // K4: GAT layer-2 aggregate + uv + packA epilogue
  k_agg<2><<<512,256,0,stream>>>(ws+WS_H2, ws+WS_ASRC2, ws+WS_ADST2, csrc, cea, starts, deg,
                                 lattr, ws+WS_AE+8, g2b, dist, markov, ws);
  // K5: sk + packB + Wc2->bf16
  k_skpack<<<512,256,0,stream>>>(Wc1, bc1, bes, Wweek, Wcap, Wveh, wd, vh, cp, Wc2, ws);
  // K6/K7: decoder MFMA GEMMs
  gemm_mfma<true,true><<<dim3(8,8),256,0,stream>>>((const bf16*)(ws+WS_APACK), (const bf16*)(ws+WS_BPACK),
                                                   ws+WS_K, nullptr, (bf16*)(ws+WS_OUT1), 512, 512, K1);
  gemm_mfma<false,false><<<dim3(8,8),256,0,stream>>>((const bf16*)(ws+WS_OUT1), (const bf16*)(ws+WS_WC2B),
                                                     bc2, out, nullptr, 512, 512, 512);
}